// Round 17
// baseline (197.002 us; speedup 1.0000x reference)
//
#include <hip/hip_runtime.h>
#include <math.h>

#define NH 16          // heads
#define HD 64          // head dim
#define NB 4           // batch
#define SQ 1024        // seq len
#define CH 1024        // channels

typedef _Float16 f16x8  __attribute__((ext_vector_type(8)));
typedef _Float16 f16x4  __attribute__((ext_vector_type(4)));
typedef float    f32x4  __attribute__((ext_vector_type(4)));

typedef const __attribute__((address_space(1))) void gvoid_t;
typedef __attribute__((address_space(3))) void lvoid_t;

// ---------- one-pass fp32 -> fp16 converter: x, Wqkv, Wp ----------
#define NQ_X   (NB * SQ * CH / 4)        // 1048576 float4s
#define NQ_WQ  (3 * CH * CH / 4)         // 786432
#define NQ_WP  (CH * CH / 4)             // 262144
__global__ __launch_bounds__(256) void k_split_all(
    const float* __restrict__ x, const float* __restrict__ wqkv,
    const float* __restrict__ wp,
    _Float16* __restrict__ xf, _Float16* __restrict__ wqf,
    _Float16* __restrict__ wpf)
{
    int i = blockIdx.x * 256 + threadIdx.x;
    const float4 v = (i < NQ_X) ? ((const float4*)x)[i]
                   : (i < NQ_X + NQ_WQ) ? ((const float4*)wqkv)[i - NQ_X]
                   : ((const float4*)wp)[i - NQ_X - NQ_WQ];
    f16x4 h;
    h[0] = (_Float16)v.x; h[1] = (_Float16)v.y;
    h[2] = (_Float16)v.z; h[3] = (_Float16)v.w;
    if (i < NQ_X)             ((f16x4*)xf)[i] = h;
    else if (i < NQ_X + NQ_WQ)((f16x4*)wqf)[i - NQ_X] = h;
    else                      ((f16x4*)wpf)[i - NQ_X - NQ_WQ] = h;
}

// ---------- single-pass fp16 MFMA GEMM: C = A @ B^T (+bias) ----------
// EPI 0: fused LN epilogue -> q,k fp16 (LN'd, q scaled), vT fp16 [B,H,D,N]
// EPI 1: plain fp32 out [M][1024]
template<int EPI>
__global__ __launch_bounds__(256) void k_mfma_gemm(
    const _Float16* __restrict__ A, const _Float16* __restrict__ B,
    const float* __restrict__ bias, float* __restrict__ outp,
    _Float16* __restrict__ qf, _Float16* __restrict__ kf, _Float16* __restrict__ vTf,
    const float* __restrict__ qg, const float* __restrict__ qb_,
    const float* __restrict__ kg, const float* __restrict__ kb_)
{
    __shared__ __align__(16) _Float16 sA[128 * 32];
    __shared__ __align__(16) _Float16 sB[128 * 32];

    const int tid = threadIdx.x;
    const int wid = tid >> 6, lane = tid & 63;
    const int wr = wid >> 1, wc = wid & 1;
    const int m0 = blockIdx.y * 128, n0 = blockIdx.x * 128;

    f32x4 acc[4][4];
    #pragma unroll
    for (int i = 0; i < 4; ++i)
        #pragma unroll
        for (int j = 0; j < 4; ++j)
            acc[i][j] = (f32x4){0.f, 0.f, 0.f, 0.f};

    // staging: wid0/1 -> A halves, wid2/3 -> B halves (4 loads each)
    const _Float16* gsrc = (wid < 2) ? A : B;
    _Float16* sdst = (wid < 2) ? sA : sB;
    const int gbase = (wid < 2) ? m0 : n0;
    const int ibase = (wid & 1) * 4;
    const int grow = gbase + (lane >> 2);
    const int gcol = (lane & 3) * 8;

    const int arow = wr * 64 + (lane & 15);
    const int brow = wc * 64 + (lane & 15);
    const int koff = (lane >> 4) * 8;

    for (int k0 = 0; k0 < CH; k0 += 32) {
        #pragma unroll
        for (int i = 0; i < 4; ++i) {
            const _Float16* g = gsrc + (size_t)(grow + (ibase + i) * 16) * CH + k0 + gcol;
            __builtin_amdgcn_global_load_lds((gvoid_t*)g,
                                             (lvoid_t*)(sdst + (ibase + i) * 512),
                                             16, 0, 0);
        }
        __syncthreads();

        f16x8 a[4], b[4];
        #pragma unroll
        for (int f = 0; f < 4; ++f) {
            a[f] = *(const f16x8*)&sA[(arow + f * 16) * 32 + koff];
            b[f] = *(const f16x8*)&sB[(brow + f * 16) * 32 + koff];
        }
        #pragma unroll
        for (int i = 0; i < 4; ++i)
            #pragma unroll
            for (int j = 0; j < 4; ++j)
                acc[i][j] = __builtin_amdgcn_mfma_f32_16x16x32_f16(a[i], b[j], acc[i][j], 0, 0, 0);
        __syncthreads();
    }

    const int crow = (lane >> 4) * 4;
    const int ccol = lane & 15;

    if (EPI == 1) {
        #pragma unroll
        for (int i = 0; i < 4; ++i) {
            #pragma unroll
            for (int j = 0; j < 4; ++j) {
                const int n = n0 + wc * 64 + j * 16 + ccol;
                const float bv = bias[n];
                #pragma unroll
                for (int r = 0; r < 4; ++r) {
                    const int m = m0 + wr * 64 + i * 16 + crow + r;
                    outp[(size_t)m * CH + n] = acc[i][j][r] + bv;
                }
            }
        }
    } else {
        const int nblk = n0 + wc * 64;
        const int sec = nblk >> 10;           // 0=q 1=k 2=v
        const int h = (nblk & 1023) >> 6;
        float bv[4];
        #pragma unroll
        for (int j = 0; j < 4; ++j) bv[j] = bias[nblk + j * 16 + ccol];

        if (sec < 2) {
            const float* gp = (sec == 0) ? qg : kg;
            const float* bp = (sec == 0) ? qb_ : kb_;
            float g4[4], b4[4];
            #pragma unroll
            for (int j = 0; j < 4; ++j) { g4[j] = gp[j*16+ccol]; b4[j] = bp[j*16+ccol]; }
            const float scale = (sec == 0) ? 0.125f : 1.0f;
            _Float16* dst = (sec == 0) ? qf : kf;
            #pragma unroll
            for (int i = 0; i < 4; ++i) {
                #pragma unroll
                for (int r = 0; r < 4; ++r) {
                    const int m = m0 + wr * 64 + i * 16 + crow + r;
                    const int b_ = m >> 10, nn = m & 1023;
                    float vals[4], s = 0.f, q2 = 0.f;
                    #pragma unroll
                    for (int j = 0; j < 4; ++j) {
                        vals[j] = acc[i][j][r] + bv[j];
                        s += vals[j]; q2 += vals[j] * vals[j];
                    }
                    #pragma unroll
                    for (int o = 1; o < 16; o <<= 1) {
                        s  += __shfl_xor(s, o, 64);
                        q2 += __shfl_xor(q2, o, 64);
                    }
                    const float mean = s * 0.015625f;
                    const float var = q2 * 0.015625f - mean * mean;
                    const float rstd = rsqrtf(var + 1e-5f);
                    #pragma unroll
                    for (int j = 0; j < 4; ++j) {
                        const float y = ((vals[j] - mean) * rstd * g4[j] + b4[j]) * scale;
                        dst[((size_t)(b_ * NH + h) * SQ + nn) * HD + j * 16 + ccol] = (_Float16)y;
                    }
                }
            }
        } else {
            #pragma unroll
            for (int i = 0; i < 4; ++i) {
                const int m0r = m0 + wr * 64 + i * 16 + crow;
                const int b_ = m0r >> 10, nn0 = m0r & 1023;
                #pragma unroll
                for (int j = 0; j < 4; ++j) {
                    f16x4 tmp;
                    #pragma unroll
                    for (int r = 0; r < 4; ++r) tmp[r] = (_Float16)(acc[i][j][r] + bv[j]);
                    *(f16x4*)&vTf[((size_t)(b_ * NH + h) * HD + j * 16 + ccol) * SQ + nn0] = tmp;
                }
            }
        }
    }
}

// ---------- fused QK^T + softmax(no-max: |logit|<=8 rigorous) + weights + PV ----------
// Phase 2 now stages K/V chunks in LDS (XOR-swizzled via pre-swizzled global
// source; LDS dest linear per global_load_lds constraint). Hot-loop reads are
// ds_read (lgkmcnt domain) -> K/V load-use never queues behind the 268MB W
// store stream (in-order vmcnt). W stores are the only hot-loop vmem ops and
// are never waited on except once per chunk at the staging barrier.
__global__ __launch_bounds__(256) void k_attn(
    const _Float16* __restrict__ q, const _Float16* __restrict__ k,
    const _Float16* __restrict__ vT, float* __restrict__ W,
    _Float16* __restrict__ opf)
{
    __shared__ __align__(16) char smem[75776];   // Kc 32K | Vc 32K | Pl 10K
    _Float16* Kc = (_Float16*)smem;              // [256 krows][64 d] 128B rows, swizzled 16B slots
    _Float16* Vc = (_Float16*)(smem + 32768);    // [64 d][256 cols] 512B rows, swizzled 16B slots
    const int L = blockIdx.x;            // 512 blocks
    const int bh   = (L & 7) * 8 + (L >> 6);
    const int xblk = (L >> 3) & 7;
    const int wid = threadIdx.x >> 6, lane = threadIdx.x & 63;
    const int row0 = xblk * 128 + wid * 32;   // this wave's 32 q-rows
    const int lr = lane & 15, lg = lane >> 4;
    _Float16* PlW = (_Float16*)(smem + 65536) + wid * 32 * 40;

    const _Float16* qh = q  + (size_t)bh * SQ * HD;
    const _Float16* kh = k  + (size_t)bh * SQ * HD;
    const _Float16* vh = vT + (size_t)bh * HD * SQ;

    f16x8 qb[2][2];
    #pragma unroll
    for (int qf = 0; qf < 2; ++qf)
        #pragma unroll
        for (int c = 0; c < 2; ++c)
            qb[qf][c] = *(const f16x8*)&qh[(size_t)(row0 + qf * 16 + lr) * HD + c * 32 + lg * 8];

    // ---- phase 1: per-q row sums of exp(s) (register K; no stores -> no
    // vmcnt coupling; untouched) ----
    float lp0 = 0.f, lp1 = 0.f;
    #pragma unroll 4
    for (int kt = 0; kt < 64; ++kt) {
        const f16x8 ka0 = *(const f16x8*)&kh[(size_t)(kt * 16 + lr) * HD + lg * 8];
        const f16x8 ka1 = *(const f16x8*)&kh[(size_t)(kt * 16 + lr) * HD + 32 + lg * 8];
        f32x4 s0 = (f32x4){0.f, 0.f, 0.f, 0.f};
        f32x4 s1 = (f32x4){0.f, 0.f, 0.f, 0.f};
        s0 = __builtin_amdgcn_mfma_f32_16x16x32_f16(ka0, qb[0][0], s0, 0, 0, 0);
        s0 = __builtin_amdgcn_mfma_f32_16x16x32_f16(ka1, qb[0][1], s0, 0, 0, 0);
        s1 = __builtin_amdgcn_mfma_f32_16x16x32_f16(ka0, qb[1][0], s1, 0, 0, 0);
        s1 = __builtin_amdgcn_mfma_f32_16x16x32_f16(ka1, qb[1][1], s1, 0, 0, 0);
        #pragma unroll
        for (int r = 0; r < 4; ++r) { lp0 += __expf(s0[r]); lp1 += __expf(s1[r]); }
    }
    lp0 += __shfl_xor(lp0, 16, 64); lp0 += __shfl_xor(lp0, 32, 64);
    lp1 += __shfl_xor(lp1, 16, 64); lp1 += __shfl_xor(lp1, 32, 64);
    const float invl0 = 1.0f / lp0;      // q = row0 + lr
    const float invl1 = 1.0f / lp1;      // q = row0 + 16 + lr

    // ---- phase 2: 4 chunks of 256 k-cols; K/V via LDS ----
    float* Wr = W + (size_t)bh * SQ * SQ;
    f32x4 opv[4][2];
    #pragma unroll
    for (int dt = 0; dt < 4; ++dt)
        #pragma unroll
        for (int qf = 0; qf < 2; ++qf)
            opv[dt][qf] = (f32x4){0.f, 0.f, 0.f, 0.f};

    for (int kc = 0; kc < 4; ++kc) {
        // stage K chunk: rows kc*256..+255; per wave 8x 1KB instrs
        const _Float16* khc = kh + (size_t)kc * 256 * HD;
        #pragma unroll
        for (int i = 0; i < 8; ++i) {
            const int krow = (wid * 8 + i) * 8 + (lane >> 3);
            const int slot = lane & 7;
            const _Float16* src = khc + (size_t)krow * HD + ((slot ^ (krow & 7)) * 8);
            __builtin_amdgcn_global_load_lds((gvoid_t*)src,
                (lvoid_t*)(Kc + (wid * 8 + i) * 512 + lane * 8), 16, 0, 0);
        }
        // stage V chunk: [64 d][256 cols] from vT; per wave 8x 1KB instrs
        #pragma unroll
        for (int i = 0; i < 8; ++i) {
            const int vrow = (wid * 8 + i) * 2 + (lane >> 5);
            const int slot = lane & 31;
            const _Float16* src = vh + (size_t)vrow * SQ + kc * 256 + ((slot ^ (vrow & 7)) * 8);
            __builtin_amdgcn_global_load_lds((gvoid_t*)src,
                (lvoid_t*)(Vc + (wid * 8 + i) * 512 + lane * 8), 16, 0, 0);
        }
        __syncthreads();

        for (int jcl = 0; jcl < 8; ++jcl) {
            // V from LDS (swizzled slots; 2-way conflicts = free)
            f16x8 vb[4];
            #pragma unroll
            for (int dt = 0; dt < 4; ++dt) {
                const int vrow = dt * 16 + lr;
                const int slot = (jcl * 4 + lg) ^ (vrow & 7);
                vb[dt] = *(const f16x8*)&Vc[vrow * 256 + slot * 8];
            }
            #pragma unroll
            for (int t = 0; t < 2; ++t) {
                const int ktl = jcl * 2 + t;
                const int kt = kc * 16 + ktl;
                const int krow = ktl * 16 + lr;
                const f16x8 ka0 = *(const f16x8*)&Kc[krow * 64 + ((lg ^ (krow & 7)) * 8)];
                const f16x8 ka1 = *(const f16x8*)&Kc[krow * 64 + (((4 + lg) ^ (krow & 7)) * 8)];
                f32x4 s0 = (f32x4){0.f, 0.f, 0.f, 0.f};
                f32x4 s1 = (f32x4){0.f, 0.f, 0.f, 0.f};
                s0 = __builtin_amdgcn_mfma_f32_16x16x32_f16(ka0, qb[0][0], s0, 0, 0, 0);
                s0 = __builtin_amdgcn_mfma_f32_16x16x32_f16(ka1, qb[0][1], s0, 0, 0, 0);
                s1 = __builtin_amdgcn_mfma_f32_16x16x32_f16(ka0, qb[1][0], s1, 0, 0, 0);
                s1 = __builtin_amdgcn_mfma_f32_16x16x32_f16(ka1, qb[1][1], s1, 0, 0, 0);
                f32x4 wv0, wv1;
                f16x4 pv0, pv1;
                #pragma unroll
                for (int r = 0; r < 4; ++r) {
                    wv0[r] = __expf(s0[r]) * invl0;  pv0[r] = (_Float16)wv0[r];
                    wv1[r] = __expf(s1[r]) * invl1;  pv1[r] = (_Float16)wv1[r];
                }
                // W stores: only vmcnt ops in hot loop; never waited on here
                *(f32x4*)&Wr[(size_t)(row0 + lr) * SQ + kt * 16 + lg * 4]      = wv0;
                *(f32x4*)&Wr[(size_t)(row0 + 16 + lr) * SQ + kt * 16 + lg * 4] = wv1;
                *(f16x4*)&PlW[lr * 40 + t * 16 + lg * 4]        = pv0;
                *(f16x4*)&PlW[(16 + lr) * 40 + t * 16 + lg * 4] = pv1;
            }
            const f16x8 pa0 = *(const f16x8*)&PlW[lr * 40 + lg * 8];
            const f16x8 pa1 = *(const f16x8*)&PlW[(16 + lr) * 40 + lg * 8];
            #pragma unroll
            for (int dt = 0; dt < 4; ++dt) {
                opv[dt][0] = __builtin_amdgcn_mfma_f32_16x16x32_f16(pa0, vb[dt], opv[dt][0], 0, 0, 0);
                opv[dt][1] = __builtin_amdgcn_mfma_f32_16x16x32_f16(pa1, vb[dt], opv[dt][1], 0, 0, 0);
            }
        }
        __syncthreads();   // all waves done reading Kc/Vc before restage
    }

    // ---- epilogue: LDS transpose (reuse Kc/Vc space) -> fp16 [B,N,C] ----
    float* OfW = (float*)smem + wid * 32 * 72;
    #pragma unroll
    for (int dt = 0; dt < 4; ++dt)
        #pragma unroll
        for (int qf = 0; qf < 2; ++qf)
            #pragma unroll
            for (int r = 0; r < 4; ++r)
                OfW[(qf * 16 + lg * 4 + r) * 72 + dt * 16 + lr] = opv[dt][qf][r];
    const int b_ = bh >> 4, h = bh & 15;
    #pragma unroll
    for (int p = 0; p < 4; ++p) {
        const int r = p * 8 + (lane >> 3);
        const int c = (lane & 7) * 8;
        f16x8 hv;
        #pragma unroll
        for (int j = 0; j < 8; ++j)
            hv[j] = (_Float16)OfW[r * 72 + c + j];
        *(f16x8*)&opf[((size_t)(b_ * SQ + row0 + r)) * CH + h * HD + c] = hv;
    }
}

extern "C" void kernel_launch(void* const* d_in, const int* in_sizes, int n_in,
                              void* d_out, int out_size, void* d_ws, size_t ws_size,
                              hipStream_t stream)
{
    const float* x    = (const float*)d_in[0];
    const float* Wqkv = (const float*)d_in[1];
    const float* bqkv = (const float*)d_in[2];
    const float* qg   = (const float*)d_in[3];
    const float* qb   = (const float*)d_in[4];
    const float* kg   = (const float*)d_in[5];
    const float* kb   = (const float*)d_in[6];
    const float* Wp   = (const float*)d_in[7];
    const float* bp   = (const float*)d_in[8];

    float* out     = (float*)d_out;                       // [B,N,C]
    float* weights = out + (size_t)NB * SQ * CH;          // [B,H,N,N]

    // ws layout (MB): xf 0-8, wqf 8-14, wpf 14-16, qf 16-24, kf 24-32,
    //                 vT 32-40, opf 40-48
    char* w = (char*)d_ws;
    _Float16* xf  = (_Float16*)w;
    _Float16* wqf = (_Float16*)(w + (((size_t)8)  << 20));
    _Float16* wpf = (_Float16*)(w + (((size_t)14) << 20));
    _Float16* qf  = (_Float16*)(w + (((size_t)16) << 20));
    _Float16* kf  = (_Float16*)(w + (((size_t)24) << 20));
    _Float16* vTf = (_Float16*)(w + (((size_t)32) << 20));
    _Float16* opf = (_Float16*)(w + (((size_t)40) << 20));

    // 0) one-pass fp32 -> fp16 conversion of x, Wqkv, Wp
    k_split_all<<<dim3((NQ_X + NQ_WQ + NQ_WP) / 256), 256, 0, stream>>>(
        x, Wqkv, Wp, xf, wqf, wpf);

    // 1) qkv GEMM (fp16 single-pass) + fused bias+LN -> q,k fp16, vT fp16
    k_mfma_gemm<0><<<dim3(24, 32), 256, 0, stream>>>(
        xf, wqf, bqkv, nullptr, qf, kf, vTf, qg, qb, kg, kb);

    // 2) fused attention: QK^T + exact softmax + weights + PV -> fp16 out
    k_attn<<<dim3(512), 256, 0, stream>>>(qf, kf, vTf, weights, opf);

    // 3) proj GEMM (fp16 single-pass)
    k_mfma_gemm<1><<<dim3(8, 32), 256, 0, stream>>>(
        opf, wpf, bp, out, nullptr, nullptr, nullptr,
        nullptr, nullptr, nullptr, nullptr);
}